// Round 1
// baseline (540.260 us; speedup 1.0000x reference)
//
#include <hip/hip_runtime.h>
#include <math.h>

#define N 4096
#define P 128
#define LDIM 32
#define EPSV 1e-6f

// ---------- weight functions (match reference) ----------
__device__ __forceinline__ float w1f(float d, float r) {
  if (d < r) { float t = d / r; float b = 1.0f - t * t; return b * b * b; }
  return 0.0f;
}
__device__ __forceinline__ float w2f(float d, float r) {
  if (d < 0.5f * r) return 1.0f;
  if (d < r) { float t = (2.0f * d - r) / r; float b = 1.0f - t * t; return b * b * b; }
  return 0.0f;
}
__device__ __forceinline__ float geluf(float a) {
  return 0.5f * a * (1.0f + erff(a * 0.70710678118654752f));
}

// ---------- K0: zero accumulators + out ----------
__global__ __launch_bounds__(256) void k_init(float* __restrict__ z, int cnt, float* __restrict__ out) {
  int i = blockIdx.x * 256 + threadIdx.x;
  if (i < cnt) z[i] = 0.0f;
  if (blockIdx.x == 0 && threadIdx.x == 0) out[0] = 0.0f;
}

// ---------- K1: row squared norms ----------
__global__ __launch_bounds__(64) void k_rownorm(const float* __restrict__ x, float* __restrict__ x2) {
  int r = blockIdx.x, t = threadIdx.x;
  float a = x[(size_t)r * P + t];
  float b = x[(size_t)r * P + t + 64];
  float s = a * a + b * b;
#pragma unroll
  for (int o = 32; o > 0; o >>= 1) s += __shfl_down(s, o);
  if (t == 0) x2[r] = s;
}

// ---------- K2: dist = sqrt(max(x2_i + x2_j - 2 x@xT, 1e-12)), atomic max ----------
__global__ __launch_bounds__(256) void k_dist(const float* __restrict__ x, const float* __restrict__ x2,
                                              float* __restrict__ dist, unsigned* __restrict__ mdb) {
  __shared__ float As[16][64];
  __shared__ float Bs[16][64];
  const int bi = blockIdx.y * 64, bj = blockIdx.x * 64;
  const int tid = threadIdx.x;
  const int tx = tid & 15, ty = tid >> 4;
  const int lrow = tid >> 2, lcol = (tid & 3) << 2;
  float acc[4][4] = {};
  for (int k0 = 0; k0 < P; k0 += 16) {
    float4 a = *(const float4*)&x[(size_t)(bi + lrow) * P + k0 + lcol];
    float4 b = *(const float4*)&x[(size_t)(bj + lrow) * P + k0 + lcol];
    As[lcol + 0][lrow] = a.x; As[lcol + 1][lrow] = a.y; As[lcol + 2][lrow] = a.z; As[lcol + 3][lrow] = a.w;
    Bs[lcol + 0][lrow] = b.x; Bs[lcol + 1][lrow] = b.y; Bs[lcol + 2][lrow] = b.z; Bs[lcol + 3][lrow] = b.w;
    __syncthreads();
#pragma unroll
    for (int kk = 0; kk < 16; ++kk) {
      float4 av = *(const float4*)&As[kk][ty * 4];
      float4 bv = *(const float4*)&Bs[kk][tx * 4];
      const float aa[4] = {av.x, av.y, av.z, av.w};
      const float bb[4] = {bv.x, bv.y, bv.z, bv.w};
#pragma unroll
      for (int u = 0; u < 4; u++)
#pragma unroll
        for (int v = 0; v < 4; v++) acc[u][v] = fmaf(aa[u], bb[v], acc[u][v]);
    }
    __syncthreads();
  }
  float xi[4], xj[4];
#pragma unroll
  for (int u = 0; u < 4; u++) xi[u] = x2[bi + ty * 4 + u];
#pragma unroll
  for (int v = 0; v < 4; v++) xj[v] = x2[bj + tx * 4 + v];
  float lmax = 0.0f;
#pragma unroll
  for (int u = 0; u < 4; u++) {
    float o[4];
#pragma unroll
    for (int v = 0; v < 4; v++) {
      float d2 = xi[u] + xj[v] - 2.0f * acc[u][v];
      float d = sqrtf(fmaxf(d2, 1e-12f));
      o[v] = d;
      lmax = fmaxf(lmax, d);
    }
    *(float4*)&dist[(size_t)(bi + ty * 4 + u) * N + bj + tx * 4] = make_float4(o[0], o[1], o[2], o[3]);
  }
  __shared__ unsigned bm;
  if (tid == 0) bm = 0u;
  __syncthreads();
  atomicMax(&bm, __float_as_uint(lmax));
  __syncthreads();
  if (tid == 0) atomicMax(mdb, bm);
}

// ---------- K3: S1[j] = sum_i w1(dist[i,j], r0e) ----------
__global__ __launch_bounds__(256) void k_s1(const float* __restrict__ dist, const float* __restrict__ r0p,
                                            const unsigned* __restrict__ mdb, float* __restrict__ S1) {
  const float md = __uint_as_float(*mdb);
  const float r = fminf(*r0p, md);
  int j = blockIdx.x * 256 + threadIdx.x;
  int i0 = blockIdx.y * (N / 32);
  float s = 0.0f;
  for (int i = i0; i < i0 + N / 32; ++i) s += w1f(dist[(size_t)i * N + j], r);
  atomicAdd(&S1[j], s);
}

// ---------- K4a/K6a: accout[j,:] += sum_i W[i,j] * x[i,:]  (MODE0: W=w1(dist), MODE1: W=beta raw) ----------
template <int MODE>
__global__ __launch_bounds__(256) void k_wtx(const float* __restrict__ Wm, const float* __restrict__ x,
                                             float* __restrict__ accout, const float* __restrict__ rp,
                                             const unsigned* __restrict__ mdb) {
  const int j0 = blockIdx.x * 32;
  const int i0 = blockIdx.y * (N / 8);
  float r = 0.0f;
  if (MODE == 0) r = fminf(*rp, __uint_as_float(*mdb));
  __shared__ float wts[32][32];
  __shared__ float xs[32][P];
  const int tid = threadIdx.x;
  const int jg = tid >> 5;   // 0..7  -> j base jg*4
  const int kg = tid & 31;   // 0..31 -> k base kg*4
  float acc[4][4] = {};
  for (int ic = i0; ic < i0 + N / 8; ic += 32) {
    {
      int row = tid >> 3;
      int cg = (tid & 7) << 2;
      float4 w4 = *(const float4*)&Wm[(size_t)(ic + row) * N + j0 + cg];
      float wv[4] = {w4.x, w4.y, w4.z, w4.w};
      if (MODE == 0) {
#pragma unroll
        for (int q = 0; q < 4; q++) wv[q] = w1f(wv[q], r);
      }
      wts[row][cg + 0] = wv[0]; wts[row][cg + 1] = wv[1]; wts[row][cg + 2] = wv[2]; wts[row][cg + 3] = wv[3];
    }
    {
      int r4 = tid >> 3;
      int c4 = (tid & 7) << 4;
      const float4* src = (const float4*)&x[(size_t)(ic + r4) * P + c4];
      float4* dst = (float4*)&xs[r4][c4];
      dst[0] = src[0]; dst[1] = src[1]; dst[2] = src[2]; dst[3] = src[3];
    }
    __syncthreads();
#pragma unroll 8
    for (int ii = 0; ii < 32; ++ii) {
      float wv[4];
#pragma unroll
      for (int u = 0; u < 4; u++) wv[u] = wts[ii][jg * 4 + u];
      float4 xv = *(const float4*)&xs[ii][kg * 4];
      const float xx[4] = {xv.x, xv.y, xv.z, xv.w};
#pragma unroll
      for (int u = 0; u < 4; u++)
#pragma unroll
        for (int v = 0; v < 4; v++) acc[u][v] = fmaf(wv[u], xx[v], acc[u][v]);
    }
    __syncthreads();
  }
#pragma unroll
  for (int u = 0; u < 4; u++)
#pragma unroll
    for (int v = 0; v < 4; v++)
      atomicAdd(&accout[(size_t)(j0 + jg * 4 + u) * P + kg * 4 + v], acc[u][v]);
}

// ---------- K4b: U = x - mu (guarded), u2 = |U|^2, cj = <x,U> ----------
__global__ __launch_bounds__(128) void k_finU(const float* __restrict__ x, const float* __restrict__ muacc,
                                              const float* __restrict__ S1, float* __restrict__ U,
                                              float* __restrict__ u2, float* __restrict__ cj) {
  int j = blockIdx.x, t = threadIdx.x;
  float s = S1[j];
  float xv = x[(size_t)j * P + t];
  float uval = 0.0f;
  if (s > 0.0f) uval = xv - muacc[(size_t)j * P + t] / s;   // s==0 -> mu NaN -> mu=y -> U=0
  U[(size_t)j * P + t] = uval;
  float a = uval * uval, b = xv * uval;
#pragma unroll
  for (int o = 32; o > 0; o >>= 1) { a += __shfl_down(a, o); b += __shfl_down(b, o); }
  __shared__ float ra[2], rb[2];
  if ((t & 63) == 0) { ra[t >> 6] = a; rb[t >> 6] = b; }
  __syncthreads();
  if (t == 0) { u2[j] = ra[0] + ra[1]; cj[j] = rb[0] + rb[1]; }
}

// ---------- K5: beta (overwrites dist in place) + S2 column sums ----------
__global__ __launch_bounds__(256) void k_beta(const float* __restrict__ x, const float* __restrict__ U,
                                              const float* __restrict__ u2, const float* __restrict__ cj,
                                              float* __restrict__ dist, const float* __restrict__ r1p,
                                              const float* __restrict__ r2p, const unsigned* __restrict__ mdb,
                                              float* __restrict__ S2) {
  __shared__ float As[16][64];
  __shared__ float Bs[16][64];
  const int bi = blockIdx.y * 64, bj = blockIdx.x * 64;
  const int tid = threadIdx.x;
  const int tx = tid & 15, ty = tid >> 4;
  const int lrow = tid >> 2, lcol = (tid & 3) << 2;
  float acc[4][4] = {};
  for (int k0 = 0; k0 < P; k0 += 16) {
    float4 a = *(const float4*)&x[(size_t)(bi + lrow) * P + k0 + lcol];
    float4 b = *(const float4*)&U[(size_t)(bj + lrow) * P + k0 + lcol];
    As[lcol + 0][lrow] = a.x; As[lcol + 1][lrow] = a.y; As[lcol + 2][lrow] = a.z; As[lcol + 3][lrow] = a.w;
    Bs[lcol + 0][lrow] = b.x; Bs[lcol + 1][lrow] = b.y; Bs[lcol + 2][lrow] = b.z; Bs[lcol + 3][lrow] = b.w;
    __syncthreads();
#pragma unroll
    for (int kk = 0; kk < 16; ++kk) {
      float4 av = *(const float4*)&As[kk][ty * 4];
      float4 bv = *(const float4*)&Bs[kk][tx * 4];
      const float aa[4] = {av.x, av.y, av.z, av.w};
      const float bb[4] = {bv.x, bv.y, bv.z, bv.w};
#pragma unroll
      for (int u = 0; u < 4; u++)
#pragma unroll
        for (int v = 0; v < 4; v++) acc[u][v] = fmaf(aa[u], bb[v], acc[u][v]);
    }
    __syncthreads();
  }
  const float md = __uint_as_float(*mdb);
  const float r1e = fminf(*r1p, md), r2e = fminf(*r2p, md);
  float cv[4], uvn[4];
#pragma unroll
  for (int v = 0; v < 4; v++) { cv[v] = cj[bj + tx * 4 + v]; uvn[v] = u2[bj + tx * 4 + v]; }
  float csum[4] = {0.0f, 0.0f, 0.0f, 0.0f};
#pragma unroll
  for (int u = 0; u < 4; u++) {
    size_t off = (size_t)(bi + ty * 4 + u) * N + bj + tx * 4;
    float4 dd = *(const float4*)&dist[off];
    const float dv4[4] = {dd.x, dd.y, dd.z, dd.w};
    float o[4];
#pragma unroll
    for (int v = 0; v < 4; v++) {
      float ps = acc[u][v] - cv[v];
      float du2 = fmaxf(ps * ps * uvn[v], EPSV);
      float d = dv4[v];
      float dvv = sqrtf(fmaxf(d * d - du2, EPSV));
      float du = sqrtf(du2);
      float b = w2f(dvv, r1e) * w2f(du, r2e);
      o[v] = b;
      csum[v] += b;
    }
    *(float4*)&dist[off] = make_float4(o[0], o[1], o[2], o[3]);
  }
  __shared__ float red[16][64];
#pragma unroll
  for (int v = 0; v < 4; v++) red[ty][tx * 4 + v] = csum[v];
  __syncthreads();
  if (ty == 0) {
#pragma unroll
    for (int v = 0; v < 4; v++) {
      float s = 0.0f;
      for (int t2 = 0; t2 < 16; t2++) s += red[t2][tx * 4 + v];
      atomicAdd(&S2[bj + tx * 4 + v], s);
    }
  }
}

// ---------- K7: e_Z normalize + autoencoder + MSE ----------
__global__ __launch_bounds__(128) void k_ae(const float* __restrict__ x, const float* __restrict__ ezacc,
                                            const float* __restrict__ S2,
                                            const float* __restrict__ We1, const float* __restrict__ be1,
                                            const float* __restrict__ We2, const float* __restrict__ be2,
                                            const float* __restrict__ Wd1, const float* __restrict__ bd1,
                                            const float* __restrict__ Wd2, const float* __restrict__ bd2,
                                            float* __restrict__ out) {
  const int r = blockIdx.x, t = threadIdx.x;
  __shared__ float ez[P], h1[LDIM], zb[LDIM], h2[LDIM];
  float s2 = S2[r];
  float xv = x[(size_t)r * P + t];
  float e = (s2 > 0.0f) ? (ezacc[(size_t)r * P + t] / s2) : xv;
  ez[t] = e;
  __syncthreads();
  if (t < LDIM) {
    float a = be1[t];
    for (int k = 0; k < P; k++) a = fmaf(We1[t * P + k], ez[k], a);
    h1[t] = geluf(a);
  }
  __syncthreads();
  if (t < LDIM) {
    float a = be2[t];
    for (int k = 0; k < LDIM; k++) a = fmaf(We2[t * LDIM + k], h1[k], a);
    zb[t] = a;
  }
  __syncthreads();
  if (t < LDIM) {
    float a = bd1[t];
    for (int k = 0; k < LDIM; k++) a = fmaf(Wd1[t * LDIM + k], zb[k], a);
    h2[t] = geluf(a);
  }
  __syncthreads();
  float a = bd2[t];
  for (int k = 0; k < LDIM; k++) a = fmaf(Wd2[t * LDIM + k], h2[k], a);
  float xh = 1.0f / (1.0f + expf(-a));
  float diff = xv - xh;
  float sq = diff * diff;
#pragma unroll
  for (int o = 32; o > 0; o >>= 1) sq += __shfl_down(sq, o);
  __shared__ float pr[2];
  if ((t & 63) == 0) pr[t >> 6] = sq;
  __syncthreads();
  if (t == 0) atomicAdd(out, (pr[0] + pr[1]) * (1.0f / ((float)N * (float)P)));
}

extern "C" void kernel_launch(void* const* d_in, const int* in_sizes, int n_in,
                              void* d_out, int out_size, void* d_ws, size_t ws_size,
                              hipStream_t stream) {
  const float* x   = (const float*)d_in[0];
  const float* r0  = (const float*)d_in[1];
  const float* r1  = (const float*)d_in[2];
  const float* r2  = (const float*)d_in[3];
  const float* We1 = (const float*)d_in[4];
  const float* be1 = (const float*)d_in[5];
  const float* We2 = (const float*)d_in[6];
  const float* be2 = (const float*)d_in[7];
  const float* Wd1 = (const float*)d_in[8];
  const float* bd1 = (const float*)d_in[9];
  const float* Wd2 = (const float*)d_in[10];
  const float* bd2 = (const float*)d_in[11];
  float* out = (float*)d_out;

  float* ws    = (float*)d_ws;
  float* dist  = ws;                         // N*N (later overwritten by beta)
  float* U     = dist + (size_t)N * N;       // N*P
  float* x2    = U + (size_t)N * P;          // N
  float* u2    = x2 + N;                     // N
  float* cjv   = u2 + N;                     // N
  float* muacc = cjv + N;                    // N*P   <- zero region start
  float* ezacc = muacc + (size_t)N * P;      // N*P
  float* S1    = ezacc + (size_t)N * P;      // N
  float* S2    = S1 + N;                     // N
  unsigned* mdb = (unsigned*)(S2 + N);       // 1

  const int zcnt = 2 * N * P + 2 * N + 1;
  hipLaunchKernelGGL(k_init, dim3((zcnt + 255) / 256), dim3(256), 0, stream, muacc, zcnt, out);
  hipLaunchKernelGGL(k_rownorm, dim3(N), dim3(64), 0, stream, x, x2);
  hipLaunchKernelGGL(k_dist, dim3(64, 64), dim3(256), 0, stream, x, x2, dist, mdb);
  hipLaunchKernelGGL(k_s1, dim3(16, 32), dim3(256), 0, stream, dist, r0, mdb, S1);
  hipLaunchKernelGGL((k_wtx<0>), dim3(N / 32, 8), dim3(256), 0, stream, dist, x, muacc, r0, mdb);
  hipLaunchKernelGGL(k_finU, dim3(N), dim3(128), 0, stream, x, muacc, S1, U, u2, cjv);
  hipLaunchKernelGGL(k_beta, dim3(64, 64), dim3(256), 0, stream, x, U, u2, cjv, dist, r1, r2, mdb, S2);
  hipLaunchKernelGGL((k_wtx<1>), dim3(N / 32, 8), dim3(256), 0, stream, dist, x, ezacc, r0, mdb);
  hipLaunchKernelGGL(k_ae, dim3(N), dim3(128), 0, stream, x, ezacc, S2, We1, be1, We2, be2, Wd1, bd1, Wd2, bd2, out);
}

// Round 2
// 351.191 us; speedup vs baseline: 1.5384x; 1.5384x over previous
//
#include <hip/hip_runtime.h>
#include <math.h>

#define N 4096
#define P 128
#define LDIM 32

typedef unsigned int u32;
typedef unsigned short u16;
typedef short s16x8 __attribute__((ext_vector_type(8)));
typedef float f32x4 __attribute__((ext_vector_type(4)));

// ---------- bf16 helpers (RNE) ----------
__device__ __forceinline__ u16 f2b(float f) {
  u32 u = __float_as_uint(f);
  u += 0x7fffu + ((u >> 16) & 1u);
  return (u16)(u >> 16);
}
__device__ __forceinline__ float b2f(u16 h) { return __uint_as_float(((u32)h) << 16); }

// ---------- weight functions (match reference) ----------
__device__ __forceinline__ float w1f(float d, float r) {
  if (d < r) { float t = d / r; float b = 1.0f - t * t; return b * b * b; }
  return 0.0f;
}
__device__ __forceinline__ float w2f(float d, float r) {
  if (d < 0.5f * r) return 1.0f;
  if (d < r) { float t = (2.0f * d - r) / r; float b = 1.0f - t * t; return b * b * b; }
  return 0.0f;
}
__device__ __forceinline__ float geluf(float a) {
  return 0.5f * a * (1.0f + erff(a * 0.70710678118654752f));
}

#define MFMA(a, b, c) __builtin_amdgcn_mfma_f32_16x16x32_bf16((a), (b), (c), 0, 0, 0)

// ---------- K0: zero accumulators + out ----------
__global__ __launch_bounds__(256) void k_init(float* __restrict__ z, int cnt, float* __restrict__ out) {
  int i = blockIdx.x * 256 + threadIdx.x;
  if (i < cnt) z[i] = 0.0f;
  if (blockIdx.x == 0 && threadIdx.x == 0) out[0] = 0.0f;
}

// ---------- K1: xb = bf16(x), xbT = transpose, x2 from bf16 values ----------
__global__ __launch_bounds__(256) void k_prep(const float* __restrict__ x, u16* __restrict__ xb,
                                              u16* __restrict__ xbT, float* __restrict__ x2) {
  __shared__ u16 tl[32][36];
  const int bi = blockIdx.x * 32, bk = blockIdx.y * 32;
  const int tid = threadIdx.x;
  const int row = tid >> 3, cs = (tid & 7) * 4;
  float4 v = *(const float4*)&x[(size_t)(bi + row) * P + bk + cs];
  u16 h0 = f2b(v.x), h1 = f2b(v.y), h2 = f2b(v.z), h3 = f2b(v.w);
  float d0 = b2f(h0), d1 = b2f(h1), d2 = b2f(h2), d3 = b2f(h3);
  float s = d0 * d0 + d1 * d1 + d2 * d2 + d3 * d3;  // norms from bf16-rounded values (cancellation consistency)
  s += __shfl_down(s, 4); s += __shfl_down(s, 2); s += __shfl_down(s, 1);
  if ((tid & 7) == 0) atomicAdd(&x2[bi + row], s);
  ushort4 o4; o4.x = h0; o4.y = h1; o4.z = h2; o4.w = h3;
  *(ushort4*)(xb + (size_t)(bi + row) * P + bk + cs) = o4;
  tl[row][cs + 0] = h0; tl[row][cs + 1] = h1; tl[row][cs + 2] = h2; tl[row][cs + 3] = h3;
  __syncthreads();
  const int orow = tid >> 3, ocs = (tid & 7) * 4;
  ushort4 t4;
  t4.x = tl[ocs + 0][orow]; t4.y = tl[ocs + 1][orow]; t4.z = tl[ocs + 2][orow]; t4.w = tl[ocs + 3][orow];
  *(ushort4*)(xbT + (size_t)(bk + orow) * N + bi + ocs) = t4;
}

// ---------- K2: dist (bf16) via MFMA xb@xbT + atomic max ----------
__global__ __launch_bounds__(256) void k_dist(const u16* __restrict__ xb, const float* __restrict__ x2,
                                              u16* __restrict__ dist, u32* __restrict__ mdb) {
  __shared__ uint4 L[4096];  // A: [0..2047], B: [2048..4095]; reused as 128x136 u16 out tile
  const int bi = blockIdx.y * 128, bj = blockIdx.x * 128;
  const int tid = threadIdx.x;
  const int lane = tid & 63, wv = tid >> 6;
  const int wi = wv >> 1, wj = wv & 1;
  const int lm = lane & 15, quad = lane >> 4;
  const uint4* ga = (const uint4*)(xb + (size_t)bi * P);
  const uint4* gb = (const uint4*)(xb + (size_t)bj * P);
#pragma unroll
  for (int it = 0; it < 8; ++it) {
    int c = it * 256 + tid;
    int row = c >> 4, ch = c & 15;
    int sw = row * 16 + (ch ^ (row & 7));
    L[sw] = ga[c];
    L[2048 + sw] = gb[c];
  }
  __syncthreads();
  f32x4 acc[4][4];
#pragma unroll
  for (int u = 0; u < 4; u++)
#pragma unroll
    for (int v = 0; v < 4; v++) acc[u][v] = {0.f, 0.f, 0.f, 0.f};
#pragma unroll
  for (int ks = 0; ks < 4; ++ks) {
    s16x8 af[4], bf[4];
#pragma unroll
    for (int u = 0; u < 4; u++) { int r = wi * 64 + u * 16 + lm; af[u] = *(const s16x8*)&L[r * 16 + ((ks * 4 + quad) ^ (r & 7))]; }
#pragma unroll
    for (int v = 0; v < 4; v++) { int r = wj * 64 + v * 16 + lm; bf[v] = *(const s16x8*)&L[2048 + r * 16 + ((ks * 4 + quad) ^ (r & 7))]; }
#pragma unroll
    for (int u = 0; u < 4; u++)
#pragma unroll
      for (int v = 0; v < 4; v++) acc[u][v] = MFMA(af[u], bf[v], acc[u][v]);
  }
  __syncthreads();
  u16* outl = (u16*)L;  // [128][136]
  float lmax = 0.0f;
#pragma unroll
  for (int u = 0; u < 4; u++)
#pragma unroll
    for (int v = 0; v < 4; v++) {
      int col = wj * 64 + v * 16 + lm;
      float xjc = x2[bj + col];
#pragma unroll
      for (int reg = 0; reg < 4; reg++) {
        int row = wi * 64 + u * 16 + quad * 4 + reg;
        float d2 = x2[bi + row] + xjc - 2.0f * acc[u][v][reg];
        float d = sqrtf(fmaxf(d2, 1e-12f));
        lmax = fmaxf(lmax, d);
        outl[row * 136 + col] = f2b(d);
      }
    }
#pragma unroll
  for (int o = 32; o > 0; o >>= 1) lmax = fmaxf(lmax, __shfl_down(lmax, o));
  if (lane == 0) atomicMax(mdb, __float_as_uint(lmax));
  __syncthreads();
#pragma unroll
  for (int it = 0; it < 8; ++it) {
    int c = it * 256 + tid;
    int row = c >> 4, ch = c & 15;
    uint4 v = *(const uint4*)&outl[row * 136 + ch * 8];
    *(uint4*)(dist + (size_t)(bi + row) * N + bj + ch * 8) = v;
  }
}

// ---------- pack transform for Wtx staging ----------
template <int MODE>
__device__ __forceinline__ u32 procpack(u32 pk, float r, float& s) {
  float lo = b2f((u16)(pk & 0xffffu));
  float hi = b2f((u16)(pk >> 16));
  if (MODE == 0) {
    u16 l2 = f2b(w1f(lo, r)), h2 = f2b(w1f(hi, r));
    lo = b2f(l2); hi = b2f(h2);
    pk = (u32)l2 | ((u32)h2 << 16);
  }
  s += lo + hi;
  return pk;
}

// ---------- K3/K6: C[j,:] += sum_i A[j,i]*x[i,:]  (MODE0: A=w1(dist), symmetric; MODE1: A=betaT) ----------
// fuses S[j] = sum_i A[j,i]
template <int MODE>
__global__ __launch_bounds__(256) void k_wtx(const u16* __restrict__ Wm, const u16* __restrict__ xbT,
                                             float* __restrict__ accout, float* __restrict__ Ssum,
                                             const float* __restrict__ rp, const u32* __restrict__ mdb) {
  __shared__ uint4 LA[640];  // 128 rows x 5 uint4 (64B data + 16B pad)
  __shared__ uint4 LB[640];
  const int j0 = blockIdx.x * 128;
  const int K0 = blockIdx.y * 256;
  const int tid = threadIdx.x;
  const int lane = tid & 63, wv = tid >> 6;
  const int wi = wv >> 1, wj = wv & 1;
  const int lm = lane & 15, quad = lane >> 4;
  float r = 0.0f;
  if (MODE == 0) r = fminf(rp[0], __uint_as_float(*mdb));
  const int srow = tid >> 1, half = tid & 1;
  float spart = 0.0f;
  f32x4 acc[4][4];
#pragma unroll
  for (int u = 0; u < 4; u++)
#pragma unroll
    for (int v = 0; v < 4; v++) acc[u][v] = {0.f, 0.f, 0.f, 0.f};
  for (int kc = 0; kc < 8; ++kc) {
    const int ic = K0 + kc * 32;
    {
      const uint4* p = (const uint4*)(Wm + (size_t)(j0 + srow) * N + ic + half * 16);
      uint4 a0 = p[0], a1 = p[1];
      a0.x = procpack<MODE>(a0.x, r, spart); a0.y = procpack<MODE>(a0.y, r, spart);
      a0.z = procpack<MODE>(a0.z, r, spart); a0.w = procpack<MODE>(a0.w, r, spart);
      a1.x = procpack<MODE>(a1.x, r, spart); a1.y = procpack<MODE>(a1.y, r, spart);
      a1.z = procpack<MODE>(a1.z, r, spart); a1.w = procpack<MODE>(a1.w, r, spart);
      LA[srow * 5 + half * 2 + 0] = a0;
      LA[srow * 5 + half * 2 + 1] = a1;
    }
    {
      const uint4* p = (const uint4*)(xbT + (size_t)srow * N + ic + half * 16);
      LB[srow * 5 + half * 2 + 0] = p[0];
      LB[srow * 5 + half * 2 + 1] = p[1];
    }
    __syncthreads();
    s16x8 af[4], bf[4];
#pragma unroll
    for (int u = 0; u < 4; u++) af[u] = *(const s16x8*)&LA[(wi * 64 + u * 16 + lm) * 5 + quad];
#pragma unroll
    for (int v = 0; v < 4; v++) bf[v] = *(const s16x8*)&LB[(wj * 64 + v * 16 + lm) * 5 + quad];
#pragma unroll
    for (int u = 0; u < 4; u++)
#pragma unroll
      for (int v = 0; v < 4; v++) acc[u][v] = MFMA(af[u], bf[v], acc[u][v]);
    __syncthreads();
  }
  atomicAdd(&Ssum[j0 + srow], spart);
#pragma unroll
  for (int u = 0; u < 4; u++)
#pragma unroll
    for (int v = 0; v < 4; v++) {
      int col = wj * 64 + v * 16 + lm;
#pragma unroll
      for (int reg = 0; reg < 4; reg++) {
        int row = wi * 64 + u * 16 + quad * 4 + reg;
        atomicAdd(&accout[(size_t)(j0 + row) * P + col], acc[u][v][reg]);
      }
    }
}

// ---------- K4: U finalize (guarded), Ub=bf16(U), u2,cj from bf16; zero muacc for ez reuse ----------
__global__ __launch_bounds__(128) void k_finU(const float* __restrict__ x, const u16* __restrict__ xb,
                                              float* __restrict__ muacc, const float* __restrict__ S1,
                                              u16* __restrict__ Ub, float* __restrict__ u2, float* __restrict__ cj) {
  const int j = blockIdx.x, t = threadIdx.x;
  float s = S1[j];
  float xv = x[(size_t)j * P + t];
  float uval = 0.0f;
  if (s > 0.0f) uval = xv - muacc[(size_t)j * P + t] / s;  // s==0 -> mu NaN -> mu=y -> U=0
  muacc[(size_t)j * P + t] = 0.0f;                          // recycle buffer as ezacc
  u16 ub = f2b(uval);
  Ub[(size_t)j * P + t] = ub;
  float uf = b2f(ub);
  float xbf = b2f(xb[(size_t)j * P + t]);
  float a = uf * uf, b = xbf * uf;
#pragma unroll
  for (int o = 32; o > 0; o >>= 1) { a += __shfl_down(a, o); b += __shfl_down(b, o); }
  __shared__ float ra[2], rb[2];
  if ((t & 63) == 0) { ra[t >> 6] = a; rb[t >> 6] = b; }
  __syncthreads();
  if (t == 0) { u2[j] = ra[0] + ra[1]; cj[j] = rb[0] + rb[1]; }
}

// ---------- K5: betaT (bf16) via MFMA ps = xb@UbT + fused weight2 epilogue, transposed store ----------
__global__ __launch_bounds__(256) void k_beta(const u16* __restrict__ xb, const u16* __restrict__ Ub,
                                              const float* __restrict__ u2, const float* __restrict__ cj,
                                              const u16* __restrict__ dist, u16* __restrict__ betaT,
                                              const float* __restrict__ r1p, const float* __restrict__ r2p,
                                              const u32* __restrict__ mdb) {
  __shared__ uint4 L[4096];
  const int bi = blockIdx.y * 128, bj = blockIdx.x * 128;
  const int tid = threadIdx.x;
  const int lane = tid & 63, wv = tid >> 6;
  const int wi = wv >> 1, wj = wv & 1;
  const int lm = lane & 15, quad = lane >> 4;
  const uint4* ga = (const uint4*)(xb + (size_t)bi * P);
  const uint4* gb = (const uint4*)(Ub + (size_t)bj * P);
#pragma unroll
  for (int it = 0; it < 8; ++it) {
    int c = it * 256 + tid;
    int row = c >> 4, ch = c & 15;
    int sw = row * 16 + (ch ^ (row & 7));
    L[sw] = ga[c];
    L[2048 + sw] = gb[c];
  }
  __syncthreads();
  f32x4 acc[4][4];
#pragma unroll
  for (int u = 0; u < 4; u++)
#pragma unroll
    for (int v = 0; v < 4; v++) acc[u][v] = {0.f, 0.f, 0.f, 0.f};
#pragma unroll
  for (int ks = 0; ks < 4; ++ks) {
    s16x8 af[4], bf[4];
#pragma unroll
    for (int u = 0; u < 4; u++) { int rr = wi * 64 + u * 16 + lm; af[u] = *(const s16x8*)&L[rr * 16 + ((ks * 4 + quad) ^ (rr & 7))]; }
#pragma unroll
    for (int v = 0; v < 4; v++) { int rr = wj * 64 + v * 16 + lm; bf[v] = *(const s16x8*)&L[2048 + rr * 16 + ((ks * 4 + quad) ^ (rr & 7))]; }
#pragma unroll
    for (int u = 0; u < 4; u++)
#pragma unroll
      for (int v = 0; v < 4; v++) acc[u][v] = MFMA(af[u], bf[v], acc[u][v]);
  }
  __syncthreads();
  const float md = __uint_as_float(*mdb);
  const float r1e = fminf(r1p[0], md), r2e = fminf(r2p[0], md);
  u16* outl = (u16*)L;  // transposed tile [j_local 128][i_local 136]
#pragma unroll
  for (int v = 0; v < 4; v++) {
    int col = wj * 64 + v * 16 + lm;
    float cjv = cj[bj + col];
    float u2v = u2[bj + col];
#pragma unroll
    for (int u = 0; u < 4; u++)
#pragma unroll
      for (int reg = 0; reg < 4; reg++) {
        int row = wi * 64 + u * 16 + quad * 4 + reg;
        float d = b2f(dist[(size_t)(bi + row) * N + bj + col]);
        float ps = acc[u][v][reg] - cjv;
        float du2 = fmaxf(ps * ps * u2v, 1e-6f);
        float dvv = sqrtf(fmaxf(d * d - du2, 1e-6f));
        float du = sqrtf(du2);
        outl[col * 136 + row] = f2b(w2f(dvv, r1e) * w2f(du, r2e));
      }
  }
  __syncthreads();
#pragma unroll
  for (int it = 0; it < 8; ++it) {
    int c = it * 256 + tid;
    int jl = c >> 4, ch = c & 15;
    uint4 v = *(const uint4*)&outl[jl * 136 + ch * 8];
    *(uint4*)(betaT + (size_t)(bj + jl) * N + bi + ch * 8) = v;
  }
}

// ---------- K7: e_Z normalize + autoencoder + MSE ----------
__global__ __launch_bounds__(128) void k_ae(const float* __restrict__ x, const float* __restrict__ ezacc,
                                            const float* __restrict__ S2,
                                            const float* __restrict__ We1, const float* __restrict__ be1,
                                            const float* __restrict__ We2, const float* __restrict__ be2,
                                            const float* __restrict__ Wd1, const float* __restrict__ bd1,
                                            const float* __restrict__ Wd2, const float* __restrict__ bd2,
                                            float* __restrict__ out) {
  const int r = blockIdx.x, t = threadIdx.x;
  __shared__ float ez[P], h1[LDIM], zb[LDIM], h2[LDIM];
  float s2 = S2[r];
  float xv = x[(size_t)r * P + t];
  float e = (s2 > 0.0f) ? (ezacc[(size_t)r * P + t] / s2) : xv;
  ez[t] = e;
  __syncthreads();
  if (t < LDIM) {
    float a = be1[t];
    for (int k = 0; k < P; k++) a = fmaf(We1[t * P + k], ez[k], a);
    h1[t] = geluf(a);
  }
  __syncthreads();
  if (t < LDIM) {
    float a = be2[t];
    for (int k = 0; k < LDIM; k++) a = fmaf(We2[t * LDIM + k], h1[k], a);
    zb[t] = a;
  }
  __syncthreads();
  if (t < LDIM) {
    float a = bd1[t];
    for (int k = 0; k < LDIM; k++) a = fmaf(Wd1[t * LDIM + k], zb[k], a);
    h2[t] = geluf(a);
  }
  __syncthreads();
  float a = bd2[t];
  for (int k = 0; k < LDIM; k++) a = fmaf(Wd2[t * LDIM + k], h2[k], a);
  float xh = 1.0f / (1.0f + expf(-a));
  float diff = xv - xh;
  float sq = diff * diff;
#pragma unroll
  for (int o = 32; o > 0; o >>= 1) sq += __shfl_down(sq, o);
  __shared__ float pr[2];
  if ((t & 63) == 0) pr[t >> 6] = sq;
  __syncthreads();
  if (t == 0) atomicAdd(out, (pr[0] + pr[1]) * (1.0f / ((float)N * (float)P)));
}

extern "C" void kernel_launch(void* const* d_in, const int* in_sizes, int n_in,
                              void* d_out, int out_size, void* d_ws, size_t ws_size,
                              hipStream_t stream) {
  const float* x   = (const float*)d_in[0];
  const float* r0  = (const float*)d_in[1];
  const float* r1  = (const float*)d_in[2];
  const float* r2  = (const float*)d_in[3];
  const float* We1 = (const float*)d_in[4];
  const float* be1 = (const float*)d_in[5];
  const float* We2 = (const float*)d_in[6];
  const float* be2 = (const float*)d_in[7];
  const float* Wd1 = (const float*)d_in[8];
  const float* bd1 = (const float*)d_in[9];
  const float* Wd2 = (const float*)d_in[10];
  const float* bd2 = (const float*)d_in[11];
  float* out = (float*)d_out;

  char* base = (char*)d_ws;
  u16* dist   = (u16*)base;                  // 33554432 B
  u16* betaT  = (u16*)(base + 33554432);     // 33554432 B
  u16* xb     = (u16*)(base + 67108864);     // 1048576 B
  u16* xbT    = (u16*)(base + 68157440);     // 1048576 B
  u16* Ub     = (u16*)(base + 69205888);     // 1048576 B
  float* muacc = (float*)(base + 70254464);  // 2097152 B (recycled as ezacc after k_finU)
  float* x2   = muacc + (size_t)N * P;       // N floats  <- contiguous zero region starts at muacc
  float* S1   = x2 + N;
  float* S2   = S1 + N;
  u32* mdb    = (u32*)(S2 + N);              // 1 (inside zero region)
  float* u2   = (float*)(mdb + 1);           // written fully by k_finU
  float* cj   = u2 + N;
  float* ezacc = muacc;

  const int zcnt = N * P + 3 * N + 1;  // muacc + x2 + S1 + S2 + mdb
  hipLaunchKernelGGL(k_init, dim3((zcnt + 255) / 256), dim3(256), 0, stream, muacc, zcnt, out);
  hipLaunchKernelGGL(k_prep, dim3(N / 32, P / 32), dim3(256), 0, stream, x, xb, xbT, x2);
  hipLaunchKernelGGL(k_dist, dim3(N / 128, N / 128), dim3(256), 0, stream, xb, x2, dist, mdb);
  hipLaunchKernelGGL((k_wtx<0>), dim3(N / 128, 16), dim3(256), 0, stream, dist, xbT, muacc, S1, r0, mdb);
  hipLaunchKernelGGL(k_finU, dim3(N), dim3(128), 0, stream, x, xb, muacc, S1, Ub, u2, cj);
  hipLaunchKernelGGL(k_beta, dim3(N / 128, N / 128), dim3(256), 0, stream, xb, Ub, u2, cj, dist, betaT, r1, r2, mdb);
  hipLaunchKernelGGL((k_wtx<1>), dim3(N / 128, 16), dim3(256), 0, stream, betaT, xbT, ezacc, S2, r0, mdb);
  hipLaunchKernelGGL(k_ae, dim3(N), dim3(128), 0, stream, x, ezacc, S2, We1, be1, We2, be2, Wd1, bd1, Wd2, bd2, out);
}